// Round 1
// baseline (630.172 us; speedup 1.0000x reference)
//
#include <hip/hip_runtime.h>
#include <math.h>

#define M_ROWS 100000
#define PITCH  264        // 256 + 8 bf16 pad: row stride 528B -> +4 banks/row, even spread

typedef __attribute__((ext_vector_type(8)))  short  short8;
typedef __attribute__((ext_vector_type(16))) float  float16v;

__device__ __forceinline__ unsigned short bf16_rne(float f) {
    unsigned u = __builtin_bit_cast(unsigned, f);
    u += 0x7FFFu + ((u >> 16) & 1u);
    return (unsigned short)(u >> 16);
}

__device__ __forceinline__ float sigmoid_fast(float x) {
    return 1.0f / (1.0f + __expf(-x));
}
__device__ __forceinline__ float tanh_fast(float x) {
    // 1 - 2/(e^{2x}+1); correct limits at +/-inf
    return 1.0f - 2.0f / (__expf(2.0f * x) + 1.0f);
}

// ---------------- prep: weights f32->bf16, mask, max-accumulator init ----------------
__global__ void prep_kernel(const float* __restrict__ wih,
                            const float* __restrict__ whh,
                            const int* __restrict__ divided,
                            unsigned short* __restrict__ wbf,
                            unsigned int* __restrict__ maxacc,
                            int* __restrict__ maskbuf)
{
    int idx = blockIdx.x * 256 + threadIdx.x;
    const int W1 = 768 * 256;                    // 196608
    if (idx < W1) {
        wbf[idx] = bf16_rne(wih[idx]);
    } else if (idx < 2 * W1) {
        wbf[idx] = bf16_rne(whh[idx - W1]);
    } else if (idx < 2 * W1 + M_ROWS) {
        int m = idx - 2 * W1;
        maskbuf[m] = (divided[3 * m] > 0) | (divided[3 * m + 1] > 0) | (divided[3 * m + 2] > 0);
    } else if (idx < 2 * W1 + M_ROWS + 256) {
        maxacc[idx - 2 * W1 - M_ROWS] = 0u;      // below ordered-map(-inf)=0x007FFFFF
    }
}

// ---------------- fused GRU: bf16 MFMA GEMMs + epilogue + masked col-max ----------------
__global__ __launch_bounds__(256, 2) void gru_main(
    const float* __restrict__ X,                 // co_embeddings [M,256]
    const float* __restrict__ H,                 // hidden_state  [M,256]
    const unsigned short* __restrict__ Wih,      // bf16 [768,256]
    const unsigned short* __restrict__ Whh,      // bf16 [768,256]
    const float* __restrict__ bih,
    const float* __restrict__ bhh,
    const int* __restrict__ maskbuf,
    float* __restrict__ hnew,                    // d_out + 256
    unsigned int* __restrict__ maxacc)
{
    __shared__ unsigned short Xs[64 * PITCH];
    __shared__ unsigned short Hs[64 * PITCH];

    const int tid  = threadIdx.x;
    const int lane = tid & 63;
    const int wave = tid >> 6;
    const int l32  = lane & 31;
    const int hi   = lane >> 5;
    const int wm   = wave & 1;                   // row half (0/1)
    const int wn   = wave >> 1;                  // col half (0/1)
    const int row0 = blockIdx.x * 64;

    // ---- stage X,H tiles f32 -> bf16 in LDS (coalesced float4 loads) ----
    #pragma unroll
    for (int i = 0; i < 16; ++i) {
        int idx = i * 256 + tid;                 // 0..4095
        int r   = idx >> 6;                      // row 0..63
        int c4  = idx & 63;                      // float4 col
        int gr  = row0 + r;
        float4 xv = make_float4(0.f, 0.f, 0.f, 0.f);
        float4 hv = make_float4(0.f, 0.f, 0.f, 0.f);
        if (gr < M_ROWS) {
            xv = reinterpret_cast<const float4*>(X)[gr * 64 + c4];
            hv = reinterpret_cast<const float4*>(H)[gr * 64 + c4];
        }
        uint2 xp, hp;
        xp.x = (unsigned)bf16_rne(xv.x) | ((unsigned)bf16_rne(xv.y) << 16);
        xp.y = (unsigned)bf16_rne(xv.z) | ((unsigned)bf16_rne(xv.w) << 16);
        hp.x = (unsigned)bf16_rne(hv.x) | ((unsigned)bf16_rne(hv.y) << 16);
        hp.y = (unsigned)bf16_rne(hv.z) | ((unsigned)bf16_rne(hv.w) << 16);
        *reinterpret_cast<uint2*>(&Xs[r * PITCH + c4 * 4]) = xp;
        *reinterpret_cast<uint2*>(&Hs[r * PITCH + c4 * 4]) = hp;
    }
    __syncthreads();

    // A-frag base for this lane: A[m=lane&31][k = hi*8 + j]  (32x32x16 layout)
    const unsigned short* xa_base = &Xs[(wm * 32 + l32) * PITCH + hi * 8];
    const unsigned short* ha_base = &Hs[(wm * 32 + l32) * PITCH + hi * 8];

    for (int jt = 0; jt < 4; ++jt) {
        const int jj = jt * 64 + wn * 32 + l32;  // hidden-unit column 0..255

        // B-frag base: B[k][n] with n=lane&31, k=hi*8+j -> row-major W[n][k]
        const unsigned short* bx0 = &Wih[jj * 256 + hi * 8];
        const unsigned short* bh0 = &Whh[jj * 256 + hi * 8];

        float16v acc[6];
        #pragma unroll
        for (int s = 0; s < 6; ++s)
            #pragma unroll
            for (int q = 0; q < 16; ++q) acc[s][q] = 0.0f;

        #pragma unroll 4
        for (int kc = 0; kc < 16; ++kc) {
            short8 ax = *reinterpret_cast<const short8*>(xa_base + kc * 16);
            short8 ah = *reinterpret_cast<const short8*>(ha_base + kc * 16);
            #pragma unroll
            for (int s = 0; s < 3; ++s) {
                short8 b = *reinterpret_cast<const short8*>(bx0 + s * 65536 + kc * 16);
                acc[s] = __builtin_amdgcn_mfma_f32_32x32x16_bf16(ax, b, acc[s], 0, 0, 0);
            }
            #pragma unroll
            for (int s = 0; s < 3; ++s) {
                short8 b = *reinterpret_cast<const short8*>(bh0 + s * 65536 + kc * 16);
                acc[3 + s] = __builtin_amdgcn_mfma_f32_32x32x16_bf16(ah, b, acc[3 + s], 0, 0, 0);
            }
        }

        // ---- fused GRU epilogue: same (reg,lane) in all 6 accs == same (m, jj) ----
        const float bir = bih[jj], biz = bih[256 + jj], bin_ = bih[512 + jj];
        const float bhr = bhh[jj], bhz = bhh[256 + jj], bhn  = bhh[512 + jj];

        float colmax = -__builtin_inff();
        #pragma unroll
        for (int reg = 0; reg < 16; ++reg) {
            int rl = (reg & 3) + 8 * (reg >> 2) + 4 * hi;   // C/D row map (m74/m101)
            int m  = row0 + wm * 32 + rl;
            if (m < M_ROWS) {
                float gir = acc[0][reg] + bir;
                float giz = acc[1][reg] + biz;
                float gin = acc[2][reg] + bin_;
                float ghr = acc[3][reg] + bhr;
                float ghz = acc[4][reg] + bhz;
                float ghn = acc[5][reg] + bhn;
                float r = sigmoid_fast(gir + ghr);
                float z = sigmoid_fast(giz + ghz);
                float n = tanh_fast(gin + r * ghn);
                float hp = H[m * 256 + jj];                 // exact f32 h (L2-hot)
                float hv = (1.0f - z) * n + z * hp;
                int mk = maskbuf[m];
                hnew[m * 256 + jj] = mk ? hv : 0.0f;
                if (mk) colmax = fmaxf(colmax, hv);
            }
        }
        // lanes l and l+32 hold the same column -> one xor-32 reduce
        colmax = fmaxf(colmax, __shfl_xor(colmax, 32));
        if (hi == 0) {
            unsigned b = __builtin_bit_cast(unsigned, colmax);
            unsigned u = (b & 0x80000000u) ? ~b : (b | 0x80000000u);  // order-preserving map
            atomicMax(&maxacc[jj], u);
        }
        // Xs/Hs are read-only after staging: no barrier needed between jt iters
    }
}

// ---------------- finalize: unmap max, add time features ----------------
__global__ void finalize_kernel(const unsigned int* __restrict__ maxacc,
                                const float* __restrict__ interval,
                                const float* __restrict__ time_w,
                                const float* __restrict__ time_b,
                                float* __restrict__ out)
{
    int j = threadIdx.x;
    unsigned u = maxacc[j];
    unsigned b = (u & 0x80000000u) ? (u & 0x7FFFFFFFu) : ~u;
    float mx = __builtin_bit_cast(float, b);
    float inv = 1.0f / logf(interval[0] + 2.718281828459045f);
    out[j] = mx + tanhf(inv * time_w[j] + time_b[j]);
}

extern "C" void kernel_launch(void* const* d_in, const int* in_sizes, int n_in,
                              void* d_out, int out_size, void* d_ws, size_t ws_size,
                              hipStream_t stream) {
    const float* interval = (const float*)d_in[0];
    const float* co       = (const float*)d_in[2];
    const int*   divided  = (const int*)d_in[3];
    const float* hidden   = (const float*)d_in[7];
    const float* wih      = (const float*)d_in[8];
    const float* whh      = (const float*)d_in[9];
    const float* bih      = (const float*)d_in[10];
    const float* bhh      = (const float*)d_in[11];
    const float* time_w   = (const float*)d_in[12];
    const float* time_b   = (const float*)d_in[13];

    float* out  = (float*)d_out;     // [256] output, then [100000*256] h_new
    float* hnew = out + 256;

    // ws layout: bf16 weights (786432 B) | maxacc (1024 B) | mask (400000 B)
    unsigned short* wbf    = (unsigned short*)d_ws;
    unsigned int*   maxacc = (unsigned int*)((char*)d_ws + 786432);
    int*            maskbuf= (int*)((char*)d_ws + 786432 + 1024);

    const int W1 = 768 * 256;
    int prep_elems = 2 * W1 + M_ROWS + 256;          // 493472
    int prep_blocks = (prep_elems + 255) / 256;      // 1928

    prep_kernel<<<prep_blocks, 256, 0, stream>>>(wih, whh, divided, wbf, maxacc, maskbuf);

    int main_blocks = (M_ROWS + 63) / 64;            // 1563
    gru_main<<<main_blocks, 256, 0, stream>>>(co, hidden, wbf, wbf + W1,
                                              bih, bhh, maskbuf, hnew, maxacc);

    finalize_kernel<<<1, 256, 0, stream>>>(maxacc, interval, time_w, time_b, out);
}